// Round 8
// baseline (121.342 us; speedup 1.0000x reference)
//
#include <hip/hip_runtime.h>
#include <hip/hip_bf16.h>

// PositionalBias: pbv[n,j,h,d] = sum_{l=1..2046} w[h,|j-l|] * v[n,l,h,d]  (j in 1..2046, else 0)
//                 z_pb[l,h]    = sum_{j=1..2046} w[h,|l-j|]               (l in 1..2046, else 0)
// B=4, S=2048, H=12, D=64. Outputs fp32: pbv (6291456) then z_pb (24576).
// SINGLE-DISPATCH fused kernel. R8 change vs R7: __builtin_amdgcn_sched_barrier(0) after the
// load-issue block each iteration, preventing the scheduler from sinking the B/A prefetch
// loads below the MFMAs (R6/R7 VGPR counts 44/76 proved it collapsed the software pipeline
// into just-in-time loads -> full L2 latency exposed serially every iteration).

typedef short short8 __attribute__((ext_vector_type(8)));   // 8 x bf16 bits (4 VGPRs)
typedef float floatx4 __attribute__((ext_vector_type(4)));  // MFMA accumulator

#define TL 2280   // A-table length per shifted copy (shorts); 8 copies = 36.5 KB LDS

__device__ __forceinline__ unsigned short f2bf(float f) {
  union { __hip_bfloat16 b; unsigned short u; } cv;
  cv.b = __float2bfloat16(f);  // RNE
  return cv.u;
}

__global__ __launch_bounds__(256, 3) void fused_kernel(const float* __restrict__ v,
                                                       const float* __restrict__ w,
                                                       float* __restrict__ out) {
  __shared__ __attribute__((aligned(16))) short Tls[8 * TL];  // 36.5 KB (aliased by zpb)

  const int bx  = blockIdx.x;
  const int tid = threadIdx.x;

  if (bx >= 768) {   // ---------------- zpb: z[i+1] = P[i] + P[2045-i] - w[h,0] ----------------
    const int h = bx - 768;
    float* wv  = (float*)Tls;          // [2048]
    float* pfx = ((float*)Tls) + 2048; // [2048]
    __shared__ float wsum[4];
    const float* wh = w + (size_t)h * 2048;
    float* zout = out + 6291456;
    for (int i = tid; i < 2048; i += 256) wv[i] = (i < 2046) ? wh[i] : 0.f;
    __syncthreads();
    const int base = tid * 8;
    float run0 = 0.f;
    #pragma unroll
    for (int k = 0; k < 8; ++k) run0 += wv[base + k];
    float x = run0;
    #pragma unroll
    for (int dd = 1; dd < 64; dd <<= 1) {
      float y = __shfl_up(x, dd);
      if ((tid & 63) >= dd) x += y;
    }
    if ((tid & 63) == 63) wsum[tid >> 6] = x;
    __syncthreads();
    const int wid4 = tid >> 6;
    float woff = 0.f;
    #pragma unroll
    for (int u = 0; u < 3; ++u) { float t = wsum[u]; if (u < wid4) woff += t; }
    float pr = x + woff - run0;
    #pragma unroll
    for (int k = 0; k < 8; ++k) { pr += wv[base + k]; pfx[base + k] = pr; }
    __syncthreads();
    for (int i = tid; i < 2046; i += 256) {
      float z = pfx[i] + pfx[2045 - i] - wv[0];
      zout[(size_t)(i + 1) * 12 + h] = z;
    }
    if (tid == 0) { zout[h] = 0.f; zout[(size_t)2047 * 12 + h] = 0.f; }
    return;
  }

  // ---------------- GEMM block: 128j x 64nd; 4 waves own private 128j x 16nd strips ------------
  const int slice = bx % 48;          // (h, ndt); same-slice blocks 48 apart -> same XCD
  const int jt    = bx / 48;          // 16
  const int ndt = slice & 3;          // batch n == ndt for the whole block
  const int h   = slice >> 2;
  const int lane = tid & 63, wid = tid >> 6;
  const int lm = lane & 15, quad = lane >> 4;
  const int jb = jt * 128;
  const int strip = ndt * 64 + wid * 16;
  const int d = (strip + lm) & 63;    // lane's head-dim index

  // B source: v[ndt][l][h][d], stride in l = 768 floats.
  const float* vrow = v + (((size_t)ndt * 2048) * 12 + h) * 64 + d;

  // raw B for t=0,1 issued before the table build (latency hidden under build)
  float r0[16], rA[16];
  {
    const int lb = quad * 8;
    #pragma unroll
    for (int i = 0; i < 8; ++i) r0[i]     = vrow[(size_t)(lb + i) * 768];
    #pragma unroll
    for (int i = 0; i < 8; ++i) r0[8 + i] = vrow[(size_t)(lb + 32 + i) * 768];
    #pragma unroll
    for (int i = 0; i < 8; ++i) rA[i]     = vrow[(size_t)(64 + lb + i) * 768];
    #pragma unroll
    for (int i = 0; i < 8; ++i) rA[8 + i] = vrow[(size_t)(64 + lb + 32 + i) * 768];
  }

  // build reversed, 8x-shifted Toeplitz table: T_c[p] = w_ext[127 + jb - p - c]
  const float* wh = w + (size_t)h * 2048;
  for (int g = tid; g < 8 * (TL / 8); g += 256) {
    int c  = g / (TL / 8);
    int p8 = (g - c * (TL / 8)) * 8;
    unsigned short buf[8] __attribute__((aligned(16)));
    #pragma unroll
    for (int i = 0; i < 8; ++i) {
      int t = 127 + jb - (p8 + i) - c;
      int a = t < 0 ? -t : t;
      buf[i] = (a <= 2045) ? f2bf(wh[a]) : (unsigned short)0;
    }
    *(short8*)&Tls[c * TL + p8] = *(const short8*)buf;
  }
  __syncthreads();   // the only block-wide sync

  // pack raw fp32 -> bf16 B-frags, zeroing the l=0 / l=2047 border columns
  auto packB = [&](int t, const float* f, short8& b0, short8& b1) {
    const int lb = t * 64 + quad * 8;
    #pragma unroll
    for (int i = 0; i < 8; ++i) {
      int la = lb + i, lc = lb + 32 + i;
      b0[i] = (la == 0 || la == 2047) ? (short)0 : (short)f2bf(f[i]);
      b1[i] = (lc == 0 || lc == 2047) ? (short)0 : (short)f2bf(f[8 + i]);
    }
  };

  // A-frag: value[i] = w_ext[j - k], j = jb + ma*16 + lm, k = l0 + kc*32 + quad*8 + i
  const int pbase = 127 + quad * 8 - lm;
  auto load_af = [&](int p0) -> short8 {
    int c = p0 & 7;
    return *(const short8*)&Tls[c * TL + (p0 - c)];
  };

  short8 afr[10];                      // afr[i] = diagonal g = i-7 relative to current l0
  #pragma unroll
  for (int i = 0; i < 10; ++i) afr[i] = load_af((i - 7) * 16 + pbase);

  short8 bc0, bc1;
  packB(0, r0, bc0, bc1);

  floatx4 acc[8];
  #pragma unroll
  for (int ma = 0; ma < 8; ++ma) acc[ma] = (floatx4){0.f, 0.f, 0.f, 0.f};

  #pragma unroll 4
  for (int t = 0; t < 32; ++t) {
    const int l0 = t * 64;
    // ---- load-issue block: raw B for t+2 (global), fresh A diagonals for t+1 (LDS) ----
    float rN[16];
    const int lb2 = ((t < 30) ? t + 2 : 31) * 64 + quad * 8;
    #pragma unroll
    for (int i = 0; i < 8; ++i) rN[i]     = vrow[(size_t)(lb2 + i) * 768];
    #pragma unroll
    for (int i = 0; i < 8; ++i) rN[8 + i] = vrow[(size_t)(lb2 + 32 + i) * 768];
    const int l0n = (t < 31) ? l0 + 64 : l0;
    short8 na0 = load_af(l0n - 16 + pbase);
    short8 na1 = load_af(l0n      + pbase);
    short8 na2 = load_af(l0n + 16 + pbase);
    short8 na3 = load_af(l0n + 32 + pbase);

    // FENCE: loads above may not sink below; MFMAs below may not hoist above.
    __builtin_amdgcn_sched_barrier(0);

    #pragma unroll
    for (int ma = 0; ma < 8; ++ma)   // kc=0: g = -ma  -> idx 7-ma
      acc[ma] = __builtin_amdgcn_mfma_f32_16x16x32_bf16(afr[7 - ma], bc0, acc[ma], 0, 0, 0);
    #pragma unroll
    for (int ma = 0; ma < 8; ++ma)   // kc=1: g = 2-ma -> idx 9-ma
      acc[ma] = __builtin_amdgcn_mfma_f32_16x16x32_bf16(afr[9 - ma], bc1, acc[ma], 0, 0, 0);

    // pack rA (raw of t+1, in flight ~2 iterations) -> current B
    packB((t < 31) ? t + 1 : 31, rA, bc0, bc1);

    // slide A window by 4 diagonals; rotate raw-B pipeline
    #pragma unroll
    for (int i = 0; i < 6; ++i) afr[i] = afr[i + 4];
    afr[6] = na0; afr[7] = na1; afr[8] = na2; afr[9] = na3;
    #pragma unroll
    for (int i = 0; i < 16; ++i) rA[i] = rN[i];
  }

  // epilogue: D row = quad*4 + r (j), col = lm (nd); zero rows j=0 and j=2047
  float* obase = out + (size_t)ndt * 1572864 + (size_t)h * 64 + d;
  #pragma unroll
  for (int ma = 0; ma < 8; ++ma) {
    floatx4 cc = acc[ma];
    #pragma unroll
    for (int r = 0; r < 4; ++r) {
      int j = jb + ma * 16 + quad * 4 + r;
      float val = (j == 0 || j == 2047) ? 0.f : cc[r];
      obase[(size_t)j * 768] = val;
    }
  }
}

extern "C" void kernel_launch(void* const* d_in, const int* in_sizes, int n_in,
                              void* d_out, int out_size, void* d_ws, size_t ws_size,
                              hipStream_t stream) {
  const float* v = (const float*)d_in[0];   // (4,2048,12,64) fp32
  const float* w = (const float*)d_in[1];   // (12,2048) fp32
  float* out = (float*)d_out;               // pbv (6291456) + z_pb (24576) fp32
  fused_kernel<<<dim3(780), 256, 0, stream>>>(v, w, out);
}